// Round 1
// baseline (117.011 us; speedup 1.0000x reference)
//
#include <hip/hip_runtime.h>
#include <math.h>

#define S 4096
#define B 16
#define SC 512          // s-chunk staged in LDS (16 x 512 fp32 = 32 KB)
#define R 8             // attention rows per wave

// ---------------------------------------------------------------------------
// Fused QKV skinny GEMM: out[b,o] = sum_s x[b,s] * W[o,s] + bias[o]
// Grid: 768 blocks (3 matrices x 256 o-groups), 256 threads (4 waves).
// Each wave owns 4 W-rows; each W element is read once from HBM (coalesced
// float4); x is staged per-chunk in LDS and reused by all 16 o-rows.
// ---------------------------------------------------------------------------
__global__ __launch_bounds__(256) void qkv_kernel(
    const float* __restrict__ x,
    const float* __restrict__ Wq, const float* __restrict__ bq,
    const float* __restrict__ Wk, const float* __restrict__ bk,
    const float* __restrict__ Wv, const float* __restrict__ bv,
    float* __restrict__ q, float* __restrict__ k, float* __restrict__ v)
{
    __shared__ float xs[B][SC];
    const int tid  = threadIdx.x;
    const int lane = tid & 63;
    const int wave = tid >> 6;
    const int bx   = blockIdx.x;        // 0..767
    const int mat  = bx >> 8;           // 0:q 1:k 2:v
    const int obase = (bx & 255) * 16;  // matrix-local row base

    const float* W    = (mat == 0) ? Wq : (mat == 1) ? Wk : Wv;
    const float* bias = (mat == 0) ? bq : (mat == 1) ? bk : bv;
    float*       out  = (mat == 0) ? q  : (mat == 1) ? k  : v;
    const int o0 = obase + wave * 4;

    float acc[4][16];
    #pragma unroll
    for (int oi = 0; oi < 4; ++oi)
        #pragma unroll
        for (int b = 0; b < 16; ++b) acc[oi][b] = 0.f;

    for (int c = 0; c < S / SC; ++c) {
        __syncthreads();
        // stage x[0:16][c*SC .. c*SC+SC) -> LDS (2048 float4s / 256 threads)
        #pragma unroll
        for (int r = 0; r < (B * SC / 4) / 256; ++r) {
            int f4 = tid + r * 256;
            int b  = f4 / (SC / 4);
            int s4 = f4 % (SC / 4);
            float4 xv = *(const float4*)&x[b * S + c * SC + s4 * 4];
            *(float4*)&xs[b][s4 * 4] = xv;
        }
        __syncthreads();
        #pragma unroll
        for (int it = 0; it < SC / 256; ++it) {
            const int sl = it * 256 + lane * 4;
            const int sg = c * SC + sl;
            float4 w0 = *(const float4*)&W[(size_t)(o0 + 0) * S + sg];
            float4 w1 = *(const float4*)&W[(size_t)(o0 + 1) * S + sg];
            float4 w2 = *(const float4*)&W[(size_t)(o0 + 2) * S + sg];
            float4 w3 = *(const float4*)&W[(size_t)(o0 + 3) * S + sg];
            #pragma unroll
            for (int b = 0; b < 16; ++b) {
                float4 xv = *(const float4*)&xs[b][sl];
                acc[0][b] = fmaf(w0.x, xv.x, acc[0][b]);
                acc[0][b] = fmaf(w0.y, xv.y, acc[0][b]);
                acc[0][b] = fmaf(w0.z, xv.z, acc[0][b]);
                acc[0][b] = fmaf(w0.w, xv.w, acc[0][b]);
                acc[1][b] = fmaf(w1.x, xv.x, acc[1][b]);
                acc[1][b] = fmaf(w1.y, xv.y, acc[1][b]);
                acc[1][b] = fmaf(w1.z, xv.z, acc[1][b]);
                acc[1][b] = fmaf(w1.w, xv.w, acc[1][b]);
                acc[2][b] = fmaf(w2.x, xv.x, acc[2][b]);
                acc[2][b] = fmaf(w2.y, xv.y, acc[2][b]);
                acc[2][b] = fmaf(w2.z, xv.z, acc[2][b]);
                acc[2][b] = fmaf(w2.w, xv.w, acc[2][b]);
                acc[3][b] = fmaf(w3.x, xv.x, acc[3][b]);
                acc[3][b] = fmaf(w3.y, xv.y, acc[3][b]);
                acc[3][b] = fmaf(w3.z, xv.z, acc[3][b]);
                acc[3][b] = fmaf(w3.w, xv.w, acc[3][b]);
            }
        }
    }

    // cross-lane reduction; lane (oi*16+b) writes output (oi,b)
    #pragma unroll
    for (int oi = 0; oi < 4; ++oi) {
        #pragma unroll
        for (int b = 0; b < 16; ++b) {
            float s = acc[oi][b];
            #pragma unroll
            for (int off = 32; off; off >>= 1) s += __shfl_xor(s, off, 64);
            if (lane == oi * 16 + b)
                out[b * S + o0 + oi] = s + bias[o0 + oi];
        }
    }
}

// ---------------------------------------------------------------------------
// Inclusive prefix max/min of k per batch row. 16 blocks x 256 threads,
// 16-element segments per thread + Hillis-Steele scan over segment extrema.
// ---------------------------------------------------------------------------
__global__ __launch_bounds__(256) void scan_kernel(
    const float* __restrict__ k,
    float* __restrict__ rmax, float* __restrict__ rmin)
{
    __shared__ float smax[256], smin[256];
    const int b = blockIdx.x, t = threadIdx.x;
    const float* kb = k + b * S;

    float seg[16];
    float lmax = -INFINITY, lmin = INFINITY;
    #pragma unroll
    for (int e = 0; e < 16; ++e) {
        seg[e] = kb[t * 16 + e];
        lmax = fmaxf(lmax, seg[e]);
        lmin = fminf(lmin, seg[e]);
    }
    smax[t] = lmax; smin[t] = lmin;
    __syncthreads();
    for (int off = 1; off < 256; off <<= 1) {
        float vx = (t >= off) ? smax[t - off] : -INFINITY;
        float vn = (t >= off) ? smin[t - off] :  INFINITY;
        __syncthreads();
        smax[t] = fmaxf(smax[t], vx);
        smin[t] = fminf(smin[t], vn);
        __syncthreads();
    }
    float runmax = (t > 0) ? smax[t - 1] : -INFINITY;
    float runmin = (t > 0) ? smin[t - 1] :  INFINITY;
    #pragma unroll
    for (int e = 0; e < 16; ++e) {
        runmax = fmaxf(runmax, seg[e]);
        runmin = fminf(runmin, seg[e]);
        rmax[b * S + t * 16 + e] = runmax;
        rmin[b * S + t * 16 + e] = runmin;
    }
}

// ---------------------------------------------------------------------------
// d=1 causal attention, single pass (row max known from prefix scan).
// Wave handles R=8 consecutive rows i0..i0+7 of one batch, sharing k/v loads.
// out[b,i] = sum_{j<=i} exp(q_i k_j - m_i) v_j / sum exp(q_i k_j - m_i)
// Tasks assigned big-i-first for load balance.
// ---------------------------------------------------------------------------
__global__ __launch_bounds__(256) void attn_kernel(
    const float* __restrict__ q, const float* __restrict__ k,
    const float* __restrict__ v,
    const float* __restrict__ rmax, const float* __restrict__ rmin,
    float* __restrict__ out)
{
    const int tid = threadIdx.x, lane = tid & 63, wave = tid >> 6;
    const int task = blockIdx.x * 4 + wave;     // 0..8191
    const int b    = task & 15;
    const int rbi  = task >> 4;                 // 0..511
    const int i0   = (511 - rbi) * R;           // descending: big rows first
    const float* kb = k + b * S;
    const float* vb = v + b * S;
    const float LOG2E = 1.4426950408889634f;

    float a[R], cc[R], den[R], num[R];
    #pragma unroll
    for (int r = 0; r < R; ++r) {
        float qi = q[b * S + i0 + r];
        float m  = (qi >= 0.f) ? qi * rmax[b * S + i0 + r]
                               : qi * rmin[b * S + i0 + r];
        a[r]  = qi * LOG2E;
        cc[r] = -m * LOG2E;
        den[r] = 0.f; num[r] = 0.f;
    }

    const int nfull = (i0 + 1) >> 8;            // full 256-wide chunks
    for (int it = 0; it < nfull; ++it) {
        const int j = it * 256 + lane * 4;
        float4 k4 = *(const float4*)&kb[j];
        float4 v4 = *(const float4*)&vb[j];
        #pragma unroll
        for (int jj = 0; jj < 4; ++jj) {
            float kx = (&k4.x)[jj], vx = (&v4.x)[jj];
            #pragma unroll
            for (int r = 0; r < R; ++r) {
                float e = exp2f(fmaf(a[r], kx, cc[r]));
                den[r] += e;
                num[r] = fmaf(e, vx, num[r]);
            }
        }
    }
    // masked tail
    const int imax = i0 + R - 1;
    for (int j = nfull * 256 + lane; j <= imax; j += 64) {
        float kx = kb[j], vx = vb[j];
        #pragma unroll
        for (int r = 0; r < R; ++r) {
            float e = (j <= i0 + r) ? exp2f(fmaf(a[r], kx, cc[r])) : 0.f;
            den[r] += e;
            num[r] = fmaf(e, vx, num[r]);
        }
    }

    #pragma unroll
    for (int r = 0; r < R; ++r) {
        float d = den[r], n = num[r];
        #pragma unroll
        for (int off = 32; off; off >>= 1) {
            d += __shfl_xor(d, off, 64);
            n += __shfl_xor(n, off, 64);
        }
        if (lane == r) out[b * S + i0 + r] = n / d;
    }
}

extern "C" void kernel_launch(void* const* d_in, const int* in_sizes, int n_in,
                              void* d_out, int out_size, void* d_ws, size_t ws_size,
                              hipStream_t stream) {
    const float* x  = (const float*)d_in[0];
    const float* Wq = (const float*)d_in[1];
    const float* bq = (const float*)d_in[2];
    const float* Wk = (const float*)d_in[3];
    const float* bk = (const float*)d_in[4];
    const float* Wv = (const float*)d_in[5];
    const float* bv = (const float*)d_in[6];
    float* out = (float*)d_out;

    float* ws   = (float*)d_ws;
    float* q    = ws;                // 16*4096
    float* k    = ws + 65536;
    float* v    = ws + 131072;
    float* rmax = ws + 196608;
    float* rmin = ws + 262144;       // total 1.25 MB scratch

    qkv_kernel<<<768, 256, 0, stream>>>(x, Wq, bq, Wk, bk, Wv, bv, q, k, v);
    scan_kernel<<<16, 256, 0, stream>>>(k, rmax, rmin);
    attn_kernel<<<2048, 256, 0, stream>>>(q, k, v, rmax, rmin, out);
}